// Round 7
// baseline (575.818 us; speedup 1.0000x reference)
//
#include <hip/hip_runtime.h>
#include <hip/hip_bf16.h>
#include <stdint.h>

// N=4096, NFEAT=1024, NHID=256, NHEADS=4, NCLASS=1024, NLAYERS=2
#define NN 4096
#define FF 1024
#define LOG2E 1.44269504088896340736f

typedef unsigned short u16;
typedef float f32x4 __attribute__((ext_vector_type(4)));
typedef __bf16 bf16x8 __attribute__((ext_vector_type(8)));
typedef u16 u16x8 __attribute__((ext_vector_type(8)));

typedef __attribute__((address_space(1))) void gvoid_t;
typedef __attribute__((address_space(3))) void lvoid_t;

__device__ __forceinline__ u16 f2b(float f) {
  __bf16 b = (__bf16)f;
  return __builtin_bit_cast(u16, b);
}
__device__ __forceinline__ float b2f(u16 u) {
  return (float)__builtin_bit_cast(__bf16, u);
}
__device__ __forceinline__ void gload_lds16(const void* g, void* l) {
  __builtin_amdgcn_global_load_lds((gvoid_t*)g, (lvoid_t*)l, 16, 0, 0);
}

// ---------------- adjacency -> bitmask [4096][128] u32 ----------------
__global__ void k_pack(const int* __restrict__ adj, uint32_t* __restrict__ bits) {
  int gw = (blockIdx.x * 256 + threadIdx.x) >> 6;
  int lane = threadIdx.x & 63;
  int row = gw >> 6;
  int j0 = (gw & 63) << 6;
  int a = adj[(long)row * NN + j0 + lane];
  unsigned long long m = __ballot(a != 0);
  if (lane == 0)
    *reinterpret_cast<unsigned long long*>(&bits[row * 128 + (j0 >> 5)]) = m;
}

// ---------------- f32 -> bf16 convert (vectorized) ----------------
__global__ void k_cvt(const float* __restrict__ in, u16* __restrict__ out, int n4) {
  int i = blockIdx.x * 256 + threadIdx.x;
  if (i >= n4) return;
  float4 v = reinterpret_cast<const float4*>(in)[i];
  ushort4 o;
  o.x = f2b(v.x); o.y = f2b(v.y); o.z = f2b(v.z); o.w = f2b(v.w);
  reinterpret_cast<ushort4*>(out)[i] = o;
}

// ------------- batched transpose+convert: out[b][c][r] = bf16(in[b][r][c]) -------------
__global__ void k_tconv(const float* __restrict__ in, u16* __restrict__ out, int R, int C) {
  __shared__ float t[32][33];
  long bs = (long)R * C;
  const float* ip = in + blockIdx.z * bs;
  u16* op = out + blockIdx.z * bs;
  int r0 = blockIdx.x * 32, c0 = blockIdx.y * 32;
  int tx = threadIdx.x, ty = threadIdx.y;  // (32,8)
#pragma unroll
  for (int k = 0; k < 4; k++)
    t[ty + k * 8][tx] = ip[(long)(r0 + ty + k * 8) * C + c0 + tx];
  __syncthreads();
#pragma unroll
  for (int k = 0; k < 4; k++)
    op[(long)(c0 + ty + k * 8) * R + r0 + tx] = f2b(t[tx][ty + k * 8]);
}

// ------------- f_src/f_dst (scaled by log2e), c-split with atomic reduce -------------
__global__ void k_fsd2(const u16* __restrict__ WhT, const float* __restrict__ a,
                       float* __restrict__ s, float* __restrict__ d, int dh) {
  int i = blockIdx.x * 256 + threadIdx.x;
  int h = blockIdx.z;
  int c0 = blockIdx.y * 32;
  const u16* w = WhT + ((long)h * dh + c0) * NN + i;
  const float* as = a + (long)h * 2 * dh + c0;
  const float* ad = as + dh;
  float ss = 0.f, dd = 0.f;
#pragma unroll
  for (int c = 0; c < 32; c++) {
    float v = b2f(w[(long)c * NN]);
    ss = fmaf(v, as[c], ss);
    dd = fmaf(v, ad[c], dd);
  }
  atomicAdd(&s[h * NN + i], ss * LOG2E);
  atomicAdd(&d[h * NN + i], dd * LOG2E);
}

// ------------- m[h][i] = lrelu(s[h][i] + max_{j in adj(i)} d[h][j]) -------------
template <int H>
__global__ void k_maxd(const uint32_t* __restrict__ bits, const float* __restrict__ s,
                       const float* __restrict__ d, float* __restrict__ m) {
  int wv = threadIdx.x >> 6, lane = threadIdx.x & 63;
  int row = blockIdx.x * 4 + wv;
  const uint32_t* br = bits + (long)row * 128;
  float mx[H];
#pragma unroll
  for (int h = 0; h < H; h++) mx[h] = -1e30f;
  for (int t = 0; t < 64; t++) {
    int j = t * 64 + lane;
    uint32_t wb = br[j >> 5];
    bool on = (wb >> (j & 31)) & 1u;
#pragma unroll
    for (int h = 0; h < H; h++) {
      float dv = d[h * NN + j];
      mx[h] = (on && dv > mx[h]) ? dv : mx[h];
    }
  }
#pragma unroll
  for (int h = 0; h < H; h++) {
    float v = mx[h];
#pragma unroll
    for (int o = 32; o >= 1; o >>= 1) v = fmaxf(v, __shfl_xor(v, o));
    if (lane == 0) {
      float e = s[h * NN + row] + v;
      m[h * NN + row] = fmaxf(e, 0.2f * e);
    }
  }
}

// ------------- P materialization: P[h][i][j] = bf16(exp2(lrelu(s+d)-m)) masked; Z[h][i] = row-sum -------------
__global__ void k_pgen(const uint32_t* __restrict__ bits, const float* __restrict__ sA,
                       const float* __restrict__ dA, const float* __restrict__ mA,
                       u16* __restrict__ P, float* __restrict__ Z) {
  int wv = threadIdx.x >> 6, lane = threadIdx.x & 63;
  int row = blockIdx.x * 4 + wv;
  int h = blockIdx.y;
  const float* dv = dA + (long)h * NN;
  float s0 = sA[h * NN + row], m0 = mA[h * NN + row];
  float Ac = s0 - m0;             // lrelu(s+d)-m = fmax(Ac+d, fma(0.2,d,Bc))
  float Bc = 0.2f * s0 - m0;
  const uint8_t* br = reinterpret_cast<const uint8_t*>(bits) + (long)row * 512;
  u16* prow = P + (long)h * NN * NN + (long)row * NN;
  float zp = 0.f;
#pragma unroll
  for (int pass = 0; pass < 8; pass++) {
    int j = pass * 512 + lane * 8;
    f32x4 dlo = *reinterpret_cast<const f32x4*>(&dv[j]);
    f32x4 dhi = *reinterpret_cast<const f32x4*>(&dv[j + 4]);
    uint32_t mb = br[j >> 3];
    u16x8 o;
#pragma unroll
    for (int e = 0; e < 8; e++) {
      float dj = (e < 4) ? dlo[e] : dhi[e - 4];
      float v = fmaxf(Ac + dj, fmaf(0.2f, dj, Bc));
      float p = ((mb >> e) & 1u) ? exp2f(v) : 0.f;
      zp += p;
      o[e] = f2b(p);
    }
    *reinterpret_cast<u16x8*>(&prow[j]) = o;
  }
#pragma unroll
  for (int off = 32; off >= 1; off >>= 1) zp += __shfl_xor(zp, off);
  if (lane == 0) Z[h * NN + row] = zp;
}

// ------------- unified dbuf MFMA kernel: C = A @ B (BT given), tile 64x128, BK=64 -------------
// grid (M/64, N/128) = (64,8) -> 512 blocks (2/CU), 4 waves 2x2 (wave = 32x64), single
// barrier per K-tile: next tile's global_load_lds issued BEFORE compute on current buf,
// so the ~500cy load latency hides under ds_read+MFMA; barrier's implicit vmcnt(0) lands it.
// EPI 0: writes CT[n][i] = bf16(C[i][n])  (feature GEMM)
// EPI 1: writes cout[i][n] = bf16(elu(C[i][n]/Z[h*NN+i])), h = n0>>8  (heads PV)
// EPI 2: xn = xin + elu(C/Z[i]); xout = xn; xbout = bf16(xn)          (out PV + residual)
template <int EPI>
__global__ __launch_bounds__(256, 2) void k_mm(const u16* __restrict__ A,
                                               const u16* __restrict__ BT, int K,
                                               const float* __restrict__ Z,
                                               u16* __restrict__ cout,
                                               const float* __restrict__ xin,
                                               float* __restrict__ xout,
                                               u16* __restrict__ xbout) {
  __shared__ __align__(16) u16 As[2][64 * 64];
  __shared__ __align__(16) u16 Bs[2][128 * 64];
  int tid = threadIdx.x;
  int w = tid >> 6, lane = tid & 63;
  int i0 = blockIdx.x * 64, n0 = blockIdx.y * 128;
  int h = (EPI == 1) ? (n0 >> 8) : 0;
  const u16* Ab = A + (long)h * NN * NN;   // EPI1: per-head P slab; else h=0
  int wr = w >> 1, wc = w & 1;
  int l15 = lane & 15, l4 = lane >> 4;

  f32x4 acc[2][4] = {};

  int srow = lane >> 3;
  int sj = ((lane & 7) ^ srow) * 8;  // pre-swizzled source chunk (chunk ^= row&7)

#define STAGE(b, kt_)                                                             \
  {                                                                               \
    int k0_ = (kt_) * 64;                                                         \
    _Pragma("unroll") for (int t = 0; t < 2; t++) {                               \
      int r = w * 16 + t * 8 + srow;                                              \
      gload_lds16(Ab + (long)(i0 + r) * K + k0_ + sj, &As[b][(w * 16 + t * 8) * 64]); \
    }                                                                             \
    _Pragma("unroll") for (int t = 0; t < 4; t++) {                               \
      int r = w * 32 + t * 8 + srow;                                              \
      gload_lds16(BT + (long)(n0 + r) * K + k0_ + sj, &Bs[b][(w * 32 + t * 8) * 64]); \
    }                                                                             \
  }

  int nkt = K >> 6;
  STAGE(0, 0);
  __syncthreads();

  for (int kt = 0; kt < nkt; kt++) {
    int cur = kt & 1;
    if (kt < nkt - 1) STAGE(cur ^ 1, kt + 1);  // overlap next-tile loads with compute
#pragma unroll
    for (int kc = 0; kc < 2; kc++) {
      bf16x8 af[2], bf[4];
#pragma unroll
      for (int mi = 0; mi < 2; mi++) {
        int r = wr * 32 + mi * 16 + l15;
        int ph = (kc * 4 + l4) ^ (r & 7);
        af[mi] = *reinterpret_cast<const bf16x8*>(&As[cur][r * 64 + ph * 8]);
      }
#pragma unroll
      for (int ni = 0; ni < 4; ni++) {
        int r = wc * 64 + ni * 16 + l15;
        int ph = (kc * 4 + l4) ^ (r & 7);
        bf[ni] = *reinterpret_cast<const bf16x8*>(&Bs[cur][r * 64 + ph * 8]);
      }
#pragma unroll
      for (int mi = 0; mi < 2; mi++)
#pragma unroll
        for (int ni = 0; ni < 4; ni++)
          acc[mi][ni] =
              __builtin_amdgcn_mfma_f32_16x16x32_bf16(af[mi], bf[ni], acc[mi][ni], 0, 0, 0);
    }
    __syncthreads();  // drains staged loads (vmcnt 0) + protects buf reuse
  }
#undef STAGE

#pragma unroll
  for (int mi = 0; mi < 2; mi++) {
    if (EPI == 0) {
      int i = i0 + wr * 32 + mi * 16 + l4 * 4;
#pragma unroll
      for (int ni = 0; ni < 4; ni++) {
        int n = n0 + wc * 64 + ni * 16 + l15;
        ushort4 o;
        o.x = f2b(acc[mi][ni][0]);
        o.y = f2b(acc[mi][ni][1]);
        o.z = f2b(acc[mi][ni][2]);
        o.w = f2b(acc[mi][ni][3]);
        *reinterpret_cast<ushort4*>(&cout[(long)n * NN + i]) = o;
      }
    } else {
#pragma unroll
      for (int r = 0; r < 4; r++) {
        int i = i0 + wr * 32 + mi * 16 + l4 * 4 + r;
        float zi = Z[h * NN + i];
#pragma unroll
        for (int ni = 0; ni < 4; ni++) {
          int col = n0 + wc * 64 + ni * 16 + l15;
          float val = acc[mi][ni][r] / zi;
          float o = val > 0.f ? val : exp2f(val * LOG2E) - 1.f;  // elu
          long idx = (long)i * FF + col;
          if (EPI == 1) {
            cout[idx] = f2b(o);
          } else {
            float xn = xin[idx] + o;
            xout[idx] = xn;
            xbout[idx] = f2b(xn);
          }
        }
      }
    }
  }
}

extern "C" void kernel_launch(void* const* d_in, const int* in_sizes, int n_in,
                              void* d_out, int out_size, void* d_ws, size_t ws_size,
                              hipStream_t stream) {
  const float* x = (const float*)d_in[0];
  const int* adj = (const int*)d_in[1];
  const float* W_heads = (const float*)d_in[2];  // [2][4][1024][256]
  const float* a_heads = (const float*)d_in[3];  // [2][4][512]
  const float* W_out = (const float*)d_in[4];    // [2][1024][1024]
  const float* a_out = (const float*)d_in[5];    // [2][2048]
  float* out = (float*)d_out;

  char* ws = (char*)d_ws;
  uint32_t* bits = (uint32_t*)(ws + 0x0);       // 2 MB
  u16* xb = (u16*)(ws + 0x200000);              // 8 MB  bf16 x / x_new
  u16* WcatT = (u16*)(ws + 0xA00000);           // 4 MB  [2][1024 n][1024 k]
  u16* WoutT = (u16*)(ws + 0xE00000);           // 4 MB
  u16* WhT = (u16*)(ws + 0x1200000);            // 8 MB  [1024][4096] (reused for Wh2)
  u16* hbuf = (u16*)(ws + 0x1A00000);           // 8 MB  h bf16 [4096][1024]
  float* xmid = (float*)(ws + 0x2200000);       // 16 MB x after layer 0
  float* s_h = (float*)(ws + 0x3200000);        // [4][4096]
  float* d_h = (float*)(ws + 0x3210000);
  float* m_h = (float*)(ws + 0x3220000);
  float* s_o = (float*)(ws + 0x3230000);        // [4096]
  float* d_o = (float*)(ws + 0x3234000);
  float* m_o = (float*)(ws + 0x3238000);
  float* Z_h = (float*)(ws + 0x3240000);        // [4][4096] f32
  float* Z_o = (float*)(ws + 0x3250000);        // [4096] f32
  u16* Pbuf = (u16*)(ws + 0x3400000);           // 128 MB  [4][4096][4096] bf16

  k_pack<<<65536, 256, 0, stream>>>(adj, bits);
  k_cvt<<<4096, 256, 0, stream>>>(x, xb, NN * FF / 4);
  k_tconv<<<dim3(32, 8, 8), dim3(32, 8), 0, stream>>>(W_heads, WcatT, 1024, 256);
  k_tconv<<<dim3(32, 32, 2), dim3(32, 8), 0, stream>>>(W_out, WoutT, 1024, 1024);

  for (int l = 0; l < 2; l++) {
    hipMemsetAsync(ws + 0x3200000, 0, 0x3C000, stream);
    k_mm<0><<<dim3(64, 8), 256, 0, stream>>>(xb, WcatT + l * 1048576, FF, nullptr, WhT,
                                             nullptr, nullptr, nullptr);
    k_fsd2<<<dim3(16, 8, 4), 256, 0, stream>>>(WhT, a_heads + l * 2048, s_h, d_h, 256);
    k_maxd<4><<<1024, 256, 0, stream>>>(bits, s_h, d_h, m_h);
    k_pgen<<<dim3(1024, 4), 256, 0, stream>>>(bits, s_h, d_h, m_h, Pbuf, Z_h);
    k_mm<1><<<dim3(64, 8), 256, 0, stream>>>(Pbuf, WhT, NN, Z_h, hbuf, nullptr, nullptr,
                                             nullptr);
    k_mm<0><<<dim3(64, 8), 256, 0, stream>>>(hbuf, WoutT + l * 1048576, FF, nullptr, WhT,
                                             nullptr, nullptr, nullptr);
    k_fsd2<<<dim3(16, 32, 1), 256, 0, stream>>>(WhT, a_out + l * 2048, s_o, d_o, 1024);
    k_maxd<1><<<1024, 256, 0, stream>>>(bits, s_o, d_o, m_o);
    k_pgen<<<dim3(1024, 1), 256, 0, stream>>>(bits, s_o, d_o, m_o, Pbuf, Z_o);
    k_mm<2><<<dim3(64, 8), 256, 0, stream>>>(Pbuf, WhT, NN, Z_o, nullptr, l ? xmid : x,
                                             l ? out : xmid, xb);
  }
}